// Round 15
// baseline (84.605 us; speedup 1.0000x reference)
//
#include <hip/hip_runtime.h>
#include <hip/hip_fp16.h>

typedef _Float16 f16x8 __attribute__((ext_vector_type(8)));
typedef _Float16 f16x4 __attribute__((ext_vector_type(4)));
typedef float f32x4 __attribute__((ext_vector_type(4)));
typedef float f32x16 __attribute__((ext_vector_type(16)));

#define D_MODEL 1024
#define SEQ 1024
#define BATCH 4
#define NH 16
#define DV 64
#define M_TOTAL (BATCH * SEQ)   // 4096
#define QBLK 128

__device__ __forceinline__ void gload16(const _Float16* g, _Float16* lds) {
    __builtin_amdgcn_global_load_lds((const __attribute__((address_space(1))) void*)g,
                                     (__attribute__((address_space(3))) void*)lds,
                                     16, 0, 0);
}

__device__ __forceinline__ unsigned pk16(float a, float b) {
    auto h = __builtin_amdgcn_cvt_pkrtz(a, b);
    unsigned r;
    __builtin_memcpy(&r, &h, 4);
    return r;
}

// ---------------- fp32 -> fp16 convert (8 elems/thread) ----------------
__global__ void cvt_f32_f16(const float* __restrict__ s, _Float16* __restrict__ d, int n) {
    int i = (blockIdx.x * blockDim.x + threadIdx.x) * 8;
    if (i >= n) return;
    float4 a = *(const float4*)(s + i);
    float4 b = *(const float4*)(s + i + 4);
    f16x8 h;
    h[0] = (_Float16)a.x; h[1] = (_Float16)a.y; h[2] = (_Float16)a.z; h[3] = (_Float16)a.w;
    h[4] = (_Float16)b.x; h[5] = (_Float16)b.y; h[6] = (_Float16)b.z; h[7] = (_Float16)b.w;
    *(f16x8*)(d + i) = h;
}

__global__ void cvt3_f32_f16(const float* __restrict__ s0, const float* __restrict__ s1,
                             const float* __restrict__ s2, _Float16* __restrict__ d0,
                             _Float16* __restrict__ d1, _Float16* __restrict__ d2, int n) {
    const float* s = (blockIdx.y == 0) ? s0 : (blockIdx.y == 1 ? s1 : s2);
    _Float16*    d = (blockIdx.y == 0) ? d0 : (blockIdx.y == 1 ? d1 : d2);
    int i = (blockIdx.x * blockDim.x + threadIdx.x) * 8;
    if (i >= n) return;
    float4 a = *(const float4*)(s + i);
    float4 b = *(const float4*)(s + i + 4);
    f16x8 h;
    h[0] = (_Float16)a.x; h[1] = (_Float16)a.y; h[2] = (_Float16)a.z; h[3] = (_Float16)a.w;
    h[4] = (_Float16)b.x; h[5] = (_Float16)b.y; h[6] = (_Float16)b.z; h[7] = (_Float16)b.w;
    *(f16x8*)(d + i) = h;
}

// ---------------- fused QKV projection GEMM: 256x256 8-phase (unchanged, known-good) ----------------
__global__ __launch_bounds__(512, 2) void qkv_gemm(
    const _Float16* __restrict__ X,
    const _Float16* __restrict__ W0, const _Float16* __restrict__ W1, const _Float16* __restrict__ W2,
    const float* __restrict__ b0, const float* __restrict__ b1, const float* __restrict__ b2,
    _Float16* __restrict__ Qo, _Float16* __restrict__ Ko, _Float16* __restrict__ Vto)
{
    __shared__ _Float16 SM[4 * 256 * 64];
#define ABASE(buf) (SM + (buf) * 16384)
#define BBASE(buf) (SM + 32768 + (buf) * 16384)

    const int tid = threadIdx.x;
    const int l = tid & 63;
    const int w = tid >> 6;
    const int wr = w >> 2, wc = w & 3;

    const int bid = blockIdx.x;
    const int nid = (bid & 7) * 24 + (bid >> 3);
    const int mt = nid & 15, ntg = nid >> 4;
    const int mat = ntg >> 2, nt = ntg & 3;
    const _Float16* Wm  = (mat == 0) ? W0 : (mat == 1 ? W1 : W2);
    const float*    bia = (mat == 0) ? b0 : (mat == 1 ? b1 : b2);
    const int m0 = mt * 256, n0 = nt * 256;

    const int str = tid >> 3;
    const int sc8 = ((tid & 7) ^ (str & 7)) * 8;
    const _Float16* xsrc = X  + (size_t)(m0 + str) * D_MODEL + sc8;
    const _Float16* wsrc = Wm + (size_t)(n0 + str) * D_MODEL + sc8;
    const int ldst = str * 64 + (tid & 7) * 8;

#define SA(buf, kt, h) do { \
    gload16(xsrc + (size_t)((h) * 128) * D_MODEL + (kt) * 64, ABASE(buf) + (h) * 8192 + ldst); \
    gload16(xsrc + (size_t)((h) * 128 + 64) * D_MODEL + (kt) * 64, ABASE(buf) + (h) * 8192 + 4096 + ldst); } while (0)
#define SB(buf, kt, h) do { \
    gload16(wsrc + (size_t)((h) * 128) * D_MODEL + (kt) * 64, BBASE(buf) + (h) * 8192 + ldst); \
    gload16(wsrc + (size_t)((h) * 128 + 64) * D_MODEL + (kt) * 64, BBASE(buf) + (h) * 8192 + 4096 + ldst); } while (0)

    const int fr = l & 15, g = l >> 4, fr7 = l & 7;
    const int wrow = wr * 128, bcol = wc * 64;

    f32x4 acc[8][4] = {};
    f16x8 b[4][2];

    SB(0, 0, 0); SB(0, 0, 1);
    SA(0, 0, 0); SA(0, 0, 1);
    SB(1, 1, 0); SB(1, 1, 1);
    asm volatile("s_waitcnt vmcnt(4)" ::: "memory");
    __builtin_amdgcn_s_barrier();

#define PHASES(BUF, TSA_BUF, TSA, TSB_BUF, TSB)                                              \
    _Pragma("unroll")                                                                        \
    for (int p = 0; p < 4; ++p) {                                                            \
        if (p == 0) {                                                                        \
            _Pragma("unroll")                                                                \
            for (int nj = 0; nj < 4; ++nj) {                                                 \
                const int rb = (bcol + nj * 16 + fr) * 64;                                   \
                b[nj][0] = *(const f16x8*)&BBASE(BUF)[rb + ((g ^ fr7) << 3)];                \
                b[nj][1] = *(const f16x8*)&BBASE(BUF)[rb + (((4 + g) ^ fr7) << 3)];          \
            }                                                                                \
        }                                                                                    \
        f16x8 aq[2][2];                                                                      \
        _Pragma("unroll")                                                                    \
        for (int q = 0; q < 2; ++q) {                                                        \
            const int ra = (wrow + (2 * p + q) * 16 + fr) * 64;                              \
            aq[q][0] = *(const f16x8*)&ABASE(BUF)[ra + ((g ^ fr7) << 3)];                    \
            aq[q][1] = *(const f16x8*)&ABASE(BUF)[ra + (((4 + g) ^ fr7) << 3)];              \
        }                                                                                    \
        if (p == 0) SA(TSA_BUF, TSA, 0);                                                     \
        else if (p == 1) SA(TSA_BUF, TSA, 1);                                                \
        else if (p == 2) SB(TSB_BUF, TSB, 0);                                                \
        else SB(TSB_BUF, TSB, 1);                                                            \
        __builtin_amdgcn_s_barrier();                                                        \
        __builtin_amdgcn_s_setprio(1);                                                       \
        _Pragma("unroll")                                                                    \
        for (int ks = 0; ks < 2; ++ks)                                                       \
            _Pragma("unroll")                                                                \
            for (int q = 0; q < 2; ++q)                                                      \
                _Pragma("unroll")                                                            \
                for (int nj = 0; nj < 4; ++nj)                                               \
                    acc[2 * p + q][nj] = __builtin_amdgcn_mfma_f32_16x16x32_f16(             \
                        aq[q][ks], b[nj][ks], acc[2 * p + q][nj], 0, 0, 0);                  \
        __builtin_amdgcn_s_setprio(0);                                                       \
        if (p == 3) asm volatile("s_waitcnt vmcnt(4)" ::: "memory");                         \
        __builtin_amdgcn_s_barrier();                                                        \
    }

    for (int it = 0; it < 8; ++it) {
        const int tA = 2 * it + 1;
        const int tN = (2 * it + 2 < 16) ? 2 * it + 2 : 15;
        const int tM = (2 * it + 3 < 16) ? 2 * it + 3 : 15;
        PHASES(0, 1, tA, 0, tN)
        PHASES(1, 0, tN, 1, tM)
    }
#undef PHASES
#undef SA
#undef SB

    if (mat != 2) {
        const float scale = (mat == 0) ? 0.125f * 1.44269504088896340736f : 1.0f;
#pragma unroll
        for (int nj = 0; nj < 4; ++nj) {
            const int o = n0 + bcol + nj * 16 + fr;
            const float bb = bia[o];
            const int h = o >> 6, dd = o & 63;
#pragma unroll
            for (int mi = 0; mi < 8; ++mi) {
#pragma unroll
                for (int r = 0; r < 4; ++r) {
                    const int m = m0 + wrow + mi * 16 + g * 4 + r;
                    const int bi = m >> 10, s = m & 1023;
                    const float v = (acc[mi][nj][r] + bb) * scale;
                    const _Float16 hv = (_Float16)v;
                    const int bh = bi * NH + h;
                    if (mat == 0) Qo[((size_t)bh * SEQ + s) * DV + dd] = hv;
                    else          Ko[((size_t)bh * SEQ + s) * DV + dd] = hv;
                }
            }
        }
    } else {
        asm volatile("s_waitcnt vmcnt(0)" ::: "memory");
        __syncthreads();
#pragma unroll
        for (int nj = 0; nj < 4; ++nj) {
            const int n = bcol + nj * 16 + fr;
            const float bb = bia[n0 + n];
#pragma unroll
            for (int mi = 0; mi < 8; ++mi) {
#pragma unroll
                for (int r = 0; r < 4; ++r) {
                    const int m = wrow + mi * 16 + g * 4 + r;
                    SM[n * 256 + ((((m >> 3) + n) & 31) << 3) + (m & 7)] =
                        (_Float16)(acc[mi][nj][r] + bb);
                }
            }
        }
        __syncthreads();
        const int bi = m0 >> 10, s0 = m0 & 1023;
#pragma unroll
        for (int itp = 0; itp < 16; ++itp) {
            const int task = itp * 512 + tid;
            const int dd = task >> 5, sc = task & 31;
            f16x8 vv = *(const f16x8*)&SM[dd * 256 + (((sc + dd) & 31) << 3)];
            const int og = n0 + dd;
            const int h = og >> 6, d = og & 63;
            const int bh = bi * NH + h;
            *(f16x8*)(Vto + ((size_t)bh * DV + d) * SEQ + s0 + sc * 8) = vv;
        }
    }
#undef ABASE
#undef BBASE
}

// ---------------- flash attention v10: v9 + PV via 32x32x16 + full unroll ----------------
// Same split-KV structure as v9 (verified): 512 thr = 2 key-groups x 4 q-waves, 4-slot ring.
// NEW: (1) PV uses mfma_f32_32x32x16_f16 (8 MFMAs/tile instead of 16 x8 => half the
// matrix-pipe time, b128 V reads). B-frag built from S^T via one half-wave exchange per
// quad: j0-3 = hl ? shfl32(u[2w+1]) : u[2w]; j4-7 = hl ? u[2w+1] : shfl32(u[2w]).
// (2) main loop fully unrolled -> all slot bases + XOR-swizzled addresses compile-time.
// (3) fmax/rsum as 4-level trees.
__global__ __launch_bounds__(512, 4) void attn(
    const _Float16* __restrict__ Q, const _Float16* __restrict__ K,
    const _Float16* __restrict__ Vt, float* __restrict__ out)
{
    __shared__ _Float16 Kb[4][64 * 64];   // ring [key][d], 32KB; reused as merge O (f32)
    __shared__ _Float16 Vb[4][64 * 64];   // ring [d][key] (V^T), 32KB; reused for m,l

    const int tid = threadIdx.x;
    const int w = tid >> 6, l = tid & 63;
    const int grp = w >> 2, wl = w & 3;
    const int q_ = l & 31, hl = l >> 5;

    const int fid = blockIdx.y * 8 + blockIdx.x;        // grid = (8, 64)
    const int nid = (fid & 7) * 64 + (fid >> 3);
    const int bh = nid >> 3, qt = nid & 7;
    const int b = bh >> 4, h = bh & 15;
    const int q0 = qt * QBLK + wl * 32;

    const int half = tid >> 8;
    const int gt = tid & 255;
    const int str = gt >> 3;
    const int scs = ((gt & 7) ^ (str & 7)) * 8;
    const int ldst = str * 64 + (gt & 7) * 8;
    const _Float16* Kg = K  + (size_t)bh * SEQ * DV;
    const _Float16* Vg = Vt + (size_t)bh * DV * SEQ;

    f16x8 qf[4];
    {
        const _Float16* qp = Q + ((size_t)bh * SEQ + q0 + q_) * DV + hl * 8;
#pragma unroll
        for (int c = 0; c < 4; ++c) qf[c] = *(const f16x8*)(qp + c * 16);
    }

    float m_run = -1e30f, l_run = 0.f;
    f32x16 acc0 = {}, acc1 = {};

#define STAGET(T) do {                                                                    \
        const int slot_ = (T) & 3;                                                        \
        gload16(Kg + (size_t)((T) * 64 + str) * DV + scs, &Kb[slot_][0] + ldst);          \
        gload16(Kg + (size_t)((T) * 64 + str + 32) * DV + scs, &Kb[slot_][32 * 64] + ldst);\
        gload16(Vg + (size_t)str * SEQ + (T) * 64 + scs, &Vb[slot_][0] + ldst);           \
        gload16(Vg + (size_t)(str + 32) * SEQ + (T) * 64 + scs, &Vb[slot_][32 * 64] + ldst);\
    } while (0)

#define QK(S, slot, kt) do {                                                              \
        S = (f32x16){};                                                                   \
        const int row = (kt) * 32 + q_;                                                   \
        _Pragma("unroll")                                                                 \
        for (int c = 0; c < 4; ++c) {                                                     \
            f16x8 kf = *(const f16x8*)&Kb[slot][row * 64 + (((c * 2 + hl) ^ (row & 7)) << 3)]; \
            S = __builtin_amdgcn_mfma_f32_32x32x16_f16(kf, qf[c], S, 0, 0, 0);            \
        }                                                                                 \
    } while (0)

#define SMPV(S, slot, kt) do {                                                            \
        float mx8[8];                                                                     \
        _Pragma("unroll")                                                                 \
        for (int j = 0; j < 8; ++j) mx8[j] = fmaxf(S[j], S[j + 8]);                       \
        float mx4a = fmaxf(mx8[0], mx8[4]), mx4b = fmaxf(mx8[1], mx8[5]);                 \
        float mx4c = fmaxf(mx8[2], mx8[6]), mx4d = fmaxf(mx8[3], mx8[7]);                 \
        const float lmax = fmaxf(fmaxf(mx4a, mx4b), fmaxf(mx4c, mx4d));                   \
        const float mm = fmaxf(lmax, __shfl_xor(lmax, 32));                               \
        if (!__all(mm - m_run <= 8.0f)) {                                                 \
            const float mn = fmaxf(m_run, mm);                                            \
            const float al = exp2f(m_run - mn);                                           \
            l_run *= al;                                                                  \
            acc0 *= al; acc1 *= al;                                                       \
            m_run = mn;                                                                   \
        }                                                                                 \
        float p[16];                                                                      \
        _Pragma("unroll")                                                                 \
        for (int r = 0; r < 16; ++r) p[r] = exp2f(S[r] - m_run);                          \
        float rs8[8];                                                                     \
        _Pragma("unroll")                                                                 \
        for (int j = 0; j < 8; ++j) rs8[j] = p[j] + p[j + 8];                             \
        float rs4a = rs8[0] + rs8[4], rs4b = rs8[1] + rs8[5];                             \
        float rs4c = rs8[2] + rs8[6], rs4d = rs8[3] + rs8[7];                             \
        l_run += (rs4a + rs4b) + (rs4c + rs4d);                                           \
        unsigned u[4][2];                                                                 \
        _Pragma("unroll")                                                                 \
        for (int G = 0; G < 4; ++G) {                                                     \
            u[G][0] = pk16(p[4 * G], p[4 * G + 1]);                                       \
            u[G][1] = pk16(p[4 * G + 2], p[4 * G + 3]);                                   \
        }                                                                                 \
        __builtin_amdgcn_s_setprio(1);                                                    \
        _Pragma("unroll")                                                                 \
        for (int wv = 0; wv < 2; ++wv) {                                                  \
            const unsigned a00 = u[2 * wv][0], a01 = u[2 * wv][1];                        \
            const unsigned a10 = u[2 * wv + 1][0], a11 = u[2 * wv + 1][1];                \
            const unsigned s00 = (unsigned)__shfl_xor((int)a00, 32);                      \
            const unsigned s01 = (unsigned)__shfl_xor((int)a01, 32);                      \
            const unsigned s10 = (unsigned)__shfl_xor((int)a10, 32);                      \
            const unsigned s11 = (unsigned)__shfl_xor((int)a11, 32);                      \
            unsigned wd[4];                                                               \
            wd[0] = hl ? s10 : a00;                                                       \
            wd[1] = hl ? s11 : a01;                                                       \
            wd[2] = hl ? a10 : s00;                                                       \
            wd[3] = hl ? a11 : s01;                                                       \
            f16x8 pb;                                                                     \
            __builtin_memcpy(&pb, wd, 16);                                                \
            const int c16 = (kt) * 4 + 2 * wv + hl;                                       \
            const int r0 = q_;                                                            \
            f16x8 v0 = *(const f16x8*)&Vb[slot][r0 * 64 + (((c16) ^ (r0 & 7)) << 3)];     \
            acc0 = __builtin_amdgcn_mfma_f32_32x32x16_f16(v0, pb, acc0, 0, 0, 0);         \
            const int r1 = 32 + q_;                                                       \
            f16x8 v1 = *(const f16x8*)&Vb[slot][r1 * 64 + (((c16) ^ (r1 & 7)) << 3)];     \
            acc1 = __builtin_amdgcn_mfma_f32_32x32x16_f16(v1, pb, acc1, 0, 0, 0);         \
        }                                                                                 \
        __builtin_amdgcn_s_setprio(0);                                                    \
    } while (0)

    // prologue: stage tiles 0 (half 0) and 1 (half 1)
    STAGET(half);
    __syncthreads();

#pragma unroll
    for (int i = 0; i < 8; ++i) {
        const int T = 2 * i + grp;
        const int slot = T & 3;
        if (i < 7) STAGET(2 * i + 2 + half);

        f32x16 s0, s1;
        QK(s0, slot, 0);
        QK(s1, slot, 1);
        SMPV(s0, slot, 0);
        SMPV(s1, slot, 1);

        __syncthreads();
    }
#undef STAGET
#undef QK
#undef SMPV

    l_run += __shfl_xor(l_run, 32);

    // ---- split-KV merge via dead tile LDS ----
    float* Ob = (float*)&Kb[0][0];
    float* Ml = (float*)&Vb[0][0];
    if (grp == 1) {
        float* dst = Ob + (wl * 64 + l) * 32;
#pragma unroll
        for (int r = 0; r < 16; ++r) { dst[r] = acc0[r]; dst[16 + r] = acc1[r]; }
        if (l < 32) {
            Ml[(wl * 32 + q_) * 2]     = m_run;
            Ml[(wl * 32 + q_) * 2 + 1] = l_run;
        }
    }
    __syncthreads();
    if (grp == 0) {
        const float m1 = Ml[(wl * 32 + q_) * 2];
        const float l1 = Ml[(wl * 32 + q_) * 2 + 1];
        const float M  = fmaxf(m_run, m1);
        const float e0 = exp2f(m_run - M);
        const float e1 = exp2f(m1 - M);
        const float inv = 1.0f / (e0 * l_run + e1 * l1);
        const float* src = Ob + (wl * 64 + l) * 32;
        float* ob = out + ((size_t)b * SEQ + q0 + q_) * D_MODEL + h * DV;
#pragma unroll
        for (int rg = 0; rg < 4; ++rg) {
            float4 v4;
            const int d0 = rg * 8 + 4 * hl;
            v4.x = (acc0[4 * rg + 0] * e0 + src[4 * rg + 0] * e1) * inv;
            v4.y = (acc0[4 * rg + 1] * e0 + src[4 * rg + 1] * e1) * inv;
            v4.z = (acc0[4 * rg + 2] * e0 + src[4 * rg + 2] * e1) * inv;
            v4.w = (acc0[4 * rg + 3] * e0 + src[4 * rg + 3] * e1) * inv;
            *(float4*)(ob + d0) = v4;
            v4.x = (acc1[4 * rg + 0] * e0 + src[16 + 4 * rg + 0] * e1) * inv;
            v4.y = (acc1[4 * rg + 1] * e0 + src[16 + 4 * rg + 1] * e1) * inv;
            v4.z = (acc1[4 * rg + 2] * e0 + src[16 + 4 * rg + 2] * e1) * inv;
            v4.w = (acc1[4 * rg + 3] * e0 + src[16 + 4 * rg + 3] * e1) * inv;
            *(float4*)(ob + 32 + d0) = v4;
        }
    }
}

extern "C" void kernel_launch(void* const* d_in, const int* in_sizes, int n_in,
                              void* d_out, int out_size, void* d_ws, size_t ws_size,
                              hipStream_t stream) {
    const float* seq = (const float*)d_in[0];
    const float* Wq  = (const float*)d_in[1];
    const float* bq  = (const float*)d_in[2];
    const float* Wk  = (const float*)d_in[3];
    const float* bk  = (const float*)d_in[4];
    const float* Wv  = (const float*)d_in[5];
    const float* bv  = (const float*)d_in[6];
    float* out = (float*)d_out;

    _Float16* seqh = (_Float16*)d_ws;
    _Float16* wqh  = seqh + (size_t)M_TOTAL * D_MODEL;
    _Float16* wkh  = wqh + (size_t)D_MODEL * D_MODEL;
    _Float16* wvh  = wkh + (size_t)D_MODEL * D_MODEL;
    _Float16* Qh   = wvh + (size_t)D_MODEL * D_MODEL;
    _Float16* Kh   = Qh + (size_t)M_TOTAL * D_MODEL;
    _Float16* Vth  = Kh + (size_t)M_TOTAL * D_MODEL;

    const int n_seq = M_TOTAL * D_MODEL;
    const int n_w   = D_MODEL * D_MODEL;
    cvt_f32_f16<<<n_seq / (256 * 8), 256, 0, stream>>>(seq, seqh, n_seq);
    cvt3_f32_f16<<<dim3(n_w / (256 * 8), 3), 256, 0, stream>>>(Wq, Wk, Wv, wqh, wkh, wvh, n_w);

    qkv_gemm<<<192, 512, 0, stream>>>(
        seqh, wqh, wkh, wvh, bq, bk, bv, Qh, Kh, Vth);

    attn<<<dim3(SEQ / QBLK, BATCH * NH), 512, 0, stream>>>(Qh, Kh, Vth, out);
}

// Round 16
// 79.533 us; speedup vs baseline: 1.0638x; 1.0638x over previous
//
#include <hip/hip_runtime.h>
#include <hip/hip_fp16.h>

typedef _Float16 f16x8 __attribute__((ext_vector_type(8)));
typedef _Float16 f16x4 __attribute__((ext_vector_type(4)));
typedef float f32x4 __attribute__((ext_vector_type(4)));
typedef float f32x16 __attribute__((ext_vector_type(16)));

#define D_MODEL 1024
#define SEQ 1024
#define BATCH 4
#define NH 16
#define DV 64
#define M_TOTAL (BATCH * SEQ)   // 4096
#define QBLK 128

__device__ __forceinline__ void gload16(const _Float16* g, _Float16* lds) {
    __builtin_amdgcn_global_load_lds((const __attribute__((address_space(1))) void*)g,
                                     (__attribute__((address_space(3))) void*)lds,
                                     16, 0, 0);
}

// ---------------- fused fp32 -> fp16 convert: seq + 3 weights in ONE launch ----------------
// blocks [0, 2048): seq (4M elems); blocks [2048, 3584): weights, 512 blocks each.
__global__ void cvt_all(const float* __restrict__ seq, const float* __restrict__ w0,
                        const float* __restrict__ w1, const float* __restrict__ w2,
                        _Float16* __restrict__ dseq, _Float16* __restrict__ d0,
                        _Float16* __restrict__ d1, _Float16* __restrict__ d2) {
    const int bid = blockIdx.x;
    const float* s;
    _Float16* d;
    int local;
    if (bid < 2048) {
        s = seq; d = dseq; local = bid;
    } else {
        const int t = bid - 2048;
        const int mat = t >> 9, lb = t & 511;
        s = (mat == 0) ? w0 : (mat == 1 ? w1 : w2);
        d = (mat == 0) ? d0 : (mat == 1 ? d1 : d2);
        local = lb;
    }
    const int i = (local * 256 + threadIdx.x) * 8;
    float4 a = *(const float4*)(s + i);
    float4 b = *(const float4*)(s + i + 4);
    f16x8 h;
    h[0] = (_Float16)a.x; h[1] = (_Float16)a.y; h[2] = (_Float16)a.z; h[3] = (_Float16)a.w;
    h[4] = (_Float16)b.x; h[5] = (_Float16)b.y; h[6] = (_Float16)b.z; h[7] = (_Float16)b.w;
    *(f16x8*)(d + i) = h;
}

// ---------------- fused QKV projection GEMM: 256x256 8-phase (unchanged, known-good) ----------------
__global__ __launch_bounds__(512, 2) void qkv_gemm(
    const _Float16* __restrict__ X,
    const _Float16* __restrict__ W0, const _Float16* __restrict__ W1, const _Float16* __restrict__ W2,
    const float* __restrict__ b0, const float* __restrict__ b1, const float* __restrict__ b2,
    _Float16* __restrict__ Qo, _Float16* __restrict__ Ko, _Float16* __restrict__ Vto)
{
    __shared__ _Float16 SM[4 * 256 * 64];
#define ABASE(buf) (SM + (buf) * 16384)
#define BBASE(buf) (SM + 32768 + (buf) * 16384)

    const int tid = threadIdx.x;
    const int l = tid & 63;
    const int w = tid >> 6;
    const int wr = w >> 2, wc = w & 3;

    const int bid = blockIdx.x;
    const int nid = (bid & 7) * 24 + (bid >> 3);
    const int mt = nid & 15, ntg = nid >> 4;
    const int mat = ntg >> 2, nt = ntg & 3;
    const _Float16* Wm  = (mat == 0) ? W0 : (mat == 1 ? W1 : W2);
    const float*    bia = (mat == 0) ? b0 : (mat == 1 ? b1 : b2);
    const int m0 = mt * 256, n0 = nt * 256;

    const int str = tid >> 3;
    const int sc8 = ((tid & 7) ^ (str & 7)) * 8;
    const _Float16* xsrc = X  + (size_t)(m0 + str) * D_MODEL + sc8;
    const _Float16* wsrc = Wm + (size_t)(n0 + str) * D_MODEL + sc8;
    const int ldst = str * 64 + (tid & 7) * 8;

#define SA(buf, kt, h) do { \
    gload16(xsrc + (size_t)((h) * 128) * D_MODEL + (kt) * 64, ABASE(buf) + (h) * 8192 + ldst); \
    gload16(xsrc + (size_t)((h) * 128 + 64) * D_MODEL + (kt) * 64, ABASE(buf) + (h) * 8192 + 4096 + ldst); } while (0)
#define SB(buf, kt, h) do { \
    gload16(wsrc + (size_t)((h) * 128) * D_MODEL + (kt) * 64, BBASE(buf) + (h) * 8192 + ldst); \
    gload16(wsrc + (size_t)((h) * 128 + 64) * D_MODEL + (kt) * 64, BBASE(buf) + (h) * 8192 + 4096 + ldst); } while (0)

    const int fr = l & 15, g = l >> 4, fr7 = l & 7;
    const int wrow = wr * 128, bcol = wc * 64;

    f32x4 acc[8][4] = {};
    f16x8 b[4][2];

    SB(0, 0, 0); SB(0, 0, 1);
    SA(0, 0, 0); SA(0, 0, 1);
    SB(1, 1, 0); SB(1, 1, 1);
    asm volatile("s_waitcnt vmcnt(4)" ::: "memory");
    __builtin_amdgcn_s_barrier();

#define PHASES(BUF, TSA_BUF, TSA, TSB_BUF, TSB)                                              \
    _Pragma("unroll")                                                                        \
    for (int p = 0; p < 4; ++p) {                                                            \
        if (p == 0) {                                                                        \
            _Pragma("unroll")                                                                \
            for (int nj = 0; nj < 4; ++nj) {                                                 \
                const int rb = (bcol + nj * 16 + fr) * 64;                                   \
                b[nj][0] = *(const f16x8*)&BBASE(BUF)[rb + ((g ^ fr7) << 3)];                \
                b[nj][1] = *(const f16x8*)&BBASE(BUF)[rb + (((4 + g) ^ fr7) << 3)];          \
            }                                                                                \
        }                                                                                    \
        f16x8 aq[2][2];                                                                      \
        _Pragma("unroll")                                                                    \
        for (int q = 0; q < 2; ++q) {                                                        \
            const int ra = (wrow + (2 * p + q) * 16 + fr) * 64;                              \
            aq[q][0] = *(const f16x8*)&ABASE(BUF)[ra + ((g ^ fr7) << 3)];                    \
            aq[q][1] = *(const f16x8*)&ABASE(BUF)[ra + (((4 + g) ^ fr7) << 3)];              \
        }                                                                                    \
        if (p == 0) SA(TSA_BUF, TSA, 0);                                                     \
        else if (p == 1) SA(TSA_BUF, TSA, 1);                                                \
        else if (p == 2) SB(TSB_BUF, TSB, 0);                                                \
        else SB(TSB_BUF, TSB, 1);                                                            \
        __builtin_amdgcn_s_barrier();                                                        \
        __builtin_amdgcn_s_setprio(1);                                                       \
        _Pragma("unroll")                                                                    \
        for (int ks = 0; ks < 2; ++ks)                                                       \
            _Pragma("unroll")                                                                \
            for (int q = 0; q < 2; ++q)                                                      \
                _Pragma("unroll")                                                            \
                for (int nj = 0; nj < 4; ++nj)                                               \
                    acc[2 * p + q][nj] = __builtin_amdgcn_mfma_f32_16x16x32_f16(             \
                        aq[q][ks], b[nj][ks], acc[2 * p + q][nj], 0, 0, 0);                  \
        __builtin_amdgcn_s_setprio(0);                                                       \
        if (p == 3) asm volatile("s_waitcnt vmcnt(4)" ::: "memory");                         \
        __builtin_amdgcn_s_barrier();                                                        \
    }

    for (int it = 0; it < 8; ++it) {
        const int tA = 2 * it + 1;
        const int tN = (2 * it + 2 < 16) ? 2 * it + 2 : 15;
        const int tM = (2 * it + 3 < 16) ? 2 * it + 3 : 15;
        PHASES(0, 1, tA, 0, tN)
        PHASES(1, 0, tN, 1, tM)
    }
#undef PHASES
#undef SA
#undef SB

    if (mat != 2) {
        const float scale = (mat == 0) ? 0.125f * 1.44269504088896340736f : 1.0f;
#pragma unroll
        for (int nj = 0; nj < 4; ++nj) {
            const int o = n0 + bcol + nj * 16 + fr;
            const float bb = bia[o];
            const int h = o >> 6, dd = o & 63;
#pragma unroll
            for (int mi = 0; mi < 8; ++mi) {
#pragma unroll
                for (int r = 0; r < 4; ++r) {
                    const int m = m0 + wrow + mi * 16 + g * 4 + r;
                    const int bi = m >> 10, s = m & 1023;
                    const float v = (acc[mi][nj][r] + bb) * scale;
                    const _Float16 hv = (_Float16)v;
                    const int bh = bi * NH + h;
                    if (mat == 0) Qo[((size_t)bh * SEQ + s) * DV + dd] = hv;
                    else          Ko[((size_t)bh * SEQ + s) * DV + dd] = hv;
                }
            }
        }
    } else {
        asm volatile("s_waitcnt vmcnt(0)" ::: "memory");
        __syncthreads();
#pragma unroll
        for (int nj = 0; nj < 4; ++nj) {
            const int n = bcol + nj * 16 + fr;
            const float bb = bia[n0 + n];
#pragma unroll
            for (int mi = 0; mi < 8; ++mi) {
#pragma unroll
                for (int r = 0; r < 4; ++r) {
                    const int m = wrow + mi * 16 + g * 4 + r;
                    SM[n * 256 + ((((m >> 3) + n) & 31) << 3) + (m & 7)] =
                        (_Float16)(acc[mi][nj][r] + bb);
                }
            }
        }
        __syncthreads();
        const int bi = m0 >> 10, s0 = m0 & 1023;
#pragma unroll
        for (int itp = 0; itp < 16; ++itp) {
            const int task = itp * 512 + tid;
            const int dd = task >> 5, sc = task & 31;
            f16x8 vv = *(const f16x8*)&SM[dd * 256 + (((sc + dd) & 31) << 3)];
            const int og = n0 + dd;
            const int h = og >> 6, d = og & 63;
            const int bh = bi * NH + h;
            *(f16x8*)(Vto + ((size_t)bh * DV + d) * SEQ + s0 + sc * 8) = vv;
        }
    }
#undef ABASE
#undef BBASE
}

// ---------------- flash attention v9 (round-14 verified best: 44.4 us) ----------------
// 512 threads = 2 key-groups x 4 q-waves. Group g computes 64-key tiles T = 2i+g (8 each)
// with private (m,l,acc); 4-slot LDS ring (64KB) streamed by all 8 waves. 32x32 MFMA,
// zero-exchange in-register P. Groups merge via dead tile LDS at the end.
__global__ __launch_bounds__(512, 4) void attn(
    const _Float16* __restrict__ Q, const _Float16* __restrict__ K,
    const _Float16* __restrict__ Vt, float* __restrict__ out)
{
    __shared__ _Float16 Kb[4][64 * 64];   // ring [key][d], 32KB; reused as merge O (f32)
    __shared__ _Float16 Vb[4][64 * 64];   // ring [d][key] (V^T), 32KB; reused for m,l

    const int tid = threadIdx.x;
    const int w = tid >> 6, l = tid & 63;
    const int grp = w >> 2, wl = w & 3;
    const int q_ = l & 31, hl = l >> 5;

    const int fid = blockIdx.y * 8 + blockIdx.x;        // grid = (8, 64)
    const int nid = (fid & 7) * 64 + (fid >> 3);
    const int bh = nid >> 3, qt = nid & 7;
    const int b = bh >> 4, h = bh & 15;
    const int q0 = qt * QBLK + wl * 32;

    const int half = tid >> 8;
    const int gt = tid & 255;
    const int str = gt >> 3;
    const int scs = ((gt & 7) ^ (str & 7)) * 8;
    const int ldst = str * 64 + (gt & 7) * 8;
    const _Float16* Kg = K  + (size_t)bh * SEQ * DV;
    const _Float16* Vg = Vt + (size_t)bh * DV * SEQ;

    f16x8 qf[4];
    {
        const _Float16* qp = Q + ((size_t)bh * SEQ + q0 + q_) * DV + hl * 8;
#pragma unroll
        for (int c = 0; c < 4; ++c) qf[c] = *(const f16x8*)(qp + c * 16);
    }

    float m_run = -1e30f, l_run = 0.f;
    f32x16 acc0 = {}, acc1 = {};

#define STAGET(T) do {                                                                    \
        const int slot_ = (T) & 3;                                                        \
        gload16(Kg + (size_t)((T) * 64 + str) * DV + scs, &Kb[slot_][0] + ldst);          \
        gload16(Kg + (size_t)((T) * 64 + str + 32) * DV + scs, &Kb[slot_][32 * 64] + ldst);\
        gload16(Vg + (size_t)str * SEQ + (T) * 64 + scs, &Vb[slot_][0] + ldst);           \
        gload16(Vg + (size_t)(str + 32) * SEQ + (T) * 64 + scs, &Vb[slot_][32 * 64] + ldst);\
    } while (0)

#define QK(S, slot, kt) do {                                                              \
        S = (f32x16){};                                                                   \
        const int row = (kt) * 32 + q_;                                                   \
        _Pragma("unroll")                                                                 \
        for (int c = 0; c < 4; ++c) {                                                     \
            f16x8 kf = *(const f16x8*)&Kb[slot][row * 64 + (((c * 2 + hl) ^ (row & 7)) << 3)]; \
            S = __builtin_amdgcn_mfma_f32_32x32x16_f16(kf, qf[c], S, 0, 0, 0);            \
        }                                                                                 \
    } while (0)

#define SMPV(S, slot, kt) do {                                                            \
        float lmax = S[0];                                                                \
        _Pragma("unroll")                                                                 \
        for (int r = 1; r < 16; ++r) lmax = fmaxf(lmax, S[r]);                            \
        const float mm = fmaxf(lmax, __shfl_xor(lmax, 32));                               \
        if (!__all(mm - m_run <= 8.0f)) {                                                 \
            const float mn = fmaxf(m_run, mm);                                            \
            const float al = exp2f(m_run - mn);                                           \
            l_run *= al;                                                                  \
            acc0 *= al; acc1 *= al;                                                       \
            m_run = mn;                                                                   \
        }                                                                                 \
        float p[16];                                                                      \
        float rsum = 0.f;                                                                 \
        _Pragma("unroll")                                                                 \
        for (int r = 0; r < 16; ++r) { p[r] = exp2f(S[r] - m_run); rsum += p[r]; }        \
        l_run += rsum;                                                                    \
        f16x4 pf[4];                                                                      \
        _Pragma("unroll")                                                                 \
        for (int G = 0; G < 4; ++G) {                                                     \
            pf[G][0] = (_Float16)p[4 * G];     pf[G][1] = (_Float16)p[4 * G + 1];         \
            pf[G][2] = (_Float16)p[4 * G + 2]; pf[G][3] = (_Float16)p[4 * G + 3];         \
        }                                                                                 \
        __builtin_amdgcn_s_setprio(1);                                                    \
        _Pragma("unroll")                                                                 \
        for (int G = 0; G < 4; ++G) {                                                     \
            const int c16 = (kt) * 4 + G;                                                 \
            const int r0 = q_;                                                            \
            f16x4 v0 = *(const f16x4*)&Vb[slot][r0 * 64 + (((c16) ^ (r0 & 7)) << 3) + hl * 4]; \
            acc0 = __builtin_amdgcn_mfma_f32_32x32x8f16(v0, pf[G], acc0, 0, 0, 0);        \
            const int r1 = 32 + q_;                                                       \
            f16x4 v1 = *(const f16x4*)&Vb[slot][r1 * 64 + (((c16) ^ (r1 & 7)) << 3) + hl * 4]; \
            acc1 = __builtin_amdgcn_mfma_f32_32x32x8f16(v1, pf[G], acc1, 0, 0, 0);        \
        }                                                                                 \
        __builtin_amdgcn_s_setprio(0);                                                    \
    } while (0)

    // prologue: stage tiles 0 (half 0) and 1 (half 1)
    STAGET(half);
    __syncthreads();

    for (int i = 0; i < 8; ++i) {
        const int T = 2 * i + grp;
        const int slot = T & 3;
        if (i < 7) STAGET(2 * i + 2 + half);

        f32x16 s0, s1;
        QK(s0, slot, 0);
        QK(s1, slot, 1);
        SMPV(s0, slot, 0);
        SMPV(s1, slot, 1);

        __syncthreads();
    }
#undef STAGET
#undef QK
#undef SMPV

    l_run += __shfl_xor(l_run, 32);

    // ---- split-KV merge via dead tile LDS ----
    float* Ob = (float*)&Kb[0][0];
    float* Ml = (float*)&Vb[0][0];
    if (grp == 1) {
        float* dst = Ob + (wl * 64 + l) * 32;
#pragma unroll
        for (int r = 0; r < 16; ++r) { dst[r] = acc0[r]; dst[16 + r] = acc1[r]; }
        if (l < 32) {
            Ml[(wl * 32 + q_) * 2]     = m_run;
            Ml[(wl * 32 + q_) * 2 + 1] = l_run;
        }
    }
    __syncthreads();
    if (grp == 0) {
        const float m1 = Ml[(wl * 32 + q_) * 2];
        const float l1 = Ml[(wl * 32 + q_) * 2 + 1];
        const float M  = fmaxf(m_run, m1);
        const float e0 = exp2f(m_run - M);
        const float e1 = exp2f(m1 - M);
        const float inv = 1.0f / (e0 * l_run + e1 * l1);
        const float* src = Ob + (wl * 64 + l) * 32;
        float* ob = out + ((size_t)b * SEQ + q0 + q_) * D_MODEL + h * DV;
#pragma unroll
        for (int rg = 0; rg < 4; ++rg) {
            float4 v4;
            const int d0 = rg * 8 + 4 * hl;
            v4.x = (acc0[4 * rg + 0] * e0 + src[4 * rg + 0] * e1) * inv;
            v4.y = (acc0[4 * rg + 1] * e0 + src[4 * rg + 1] * e1) * inv;
            v4.z = (acc0[4 * rg + 2] * e0 + src[4 * rg + 2] * e1) * inv;
            v4.w = (acc0[4 * rg + 3] * e0 + src[4 * rg + 3] * e1) * inv;
            *(float4*)(ob + d0) = v4;
            v4.x = (acc1[4 * rg + 0] * e0 + src[16 + 4 * rg + 0] * e1) * inv;
            v4.y = (acc1[4 * rg + 1] * e0 + src[16 + 4 * rg + 1] * e1) * inv;
            v4.z = (acc1[4 * rg + 2] * e0 + src[16 + 4 * rg + 2] * e1) * inv;
            v4.w = (acc1[4 * rg + 3] * e0 + src[16 + 4 * rg + 3] * e1) * inv;
            *(float4*)(ob + 32 + d0) = v4;
        }
    }
}

extern "C" void kernel_launch(void* const* d_in, const int* in_sizes, int n_in,
                              void* d_out, int out_size, void* d_ws, size_t ws_size,
                              hipStream_t stream) {
    const float* seq = (const float*)d_in[0];
    const float* Wq  = (const float*)d_in[1];
    const float* bq  = (const float*)d_in[2];
    const float* Wk  = (const float*)d_in[3];
    const float* bk  = (const float*)d_in[4];
    const float* Wv  = (const float*)d_in[5];
    const float* bv  = (const float*)d_in[6];
    float* out = (float*)d_out;

    _Float16* seqh = (_Float16*)d_ws;
    _Float16* wqh  = seqh + (size_t)M_TOTAL * D_MODEL;
    _Float16* wkh  = wqh + (size_t)D_MODEL * D_MODEL;
    _Float16* wvh  = wkh + (size_t)D_MODEL * D_MODEL;
    _Float16* Qh   = wvh + (size_t)D_MODEL * D_MODEL;
    _Float16* Kh   = Qh + (size_t)M_TOTAL * D_MODEL;
    _Float16* Vth  = Kh + (size_t)M_TOTAL * D_MODEL;

    // one fused cvt launch: 2048 blocks for seq + 3 x 512 for weights
    cvt_all<<<2048 + 3 * 512, 256, 0, stream>>>(seq, Wq, Wk, Wv, seqh, wqh, wkh, wvh);

    qkv_gemm<<<192, 512, 0, stream>>>(
        seqh, wqh, wkh, wvh, bq, bk, bv, Qh, Kh, Vth);

    attn<<<dim3(SEQ / QBLK, BATCH * NH), 512, 0, stream>>>(Qh, Kh, Vth, out);
}